// Round 11
// baseline (478.638 us; speedup 1.0000x reference)
//
#include <hip/hip_runtime.h>
#include <hip/hip_bf16.h>

// Problem constants (fixed by reference)
#define L_SEQ 1024
#define B_DLG 128
#define D_DIM 256
#define BM 16            // rows per tile
#define THREADS 512      // 8 waves: 4 producer + 4 consumer
#define KSTEPS 8         // 256 / 32
#define TPB 8            // tiles per block
#define NBLK (B_DLG * (L_SEQ / BM) / TPB)   // 1024 blocks
#define OBROW 68         // dwords per OB row (64 cols + pad), 16B aligned

typedef __attribute__((ext_vector_type(8))) short short8;   // 8 bf16 (4 VGPRs)
typedef __attribute__((ext_vector_type(4))) float f32x4;    // MFMA accumulator

__device__ __forceinline__ unsigned short f_to_bfbits(float f) {
    unsigned int u = __float_as_uint(f);
    unsigned int r = (u + 0x7FFFu + ((u >> 16) & 1u)) >> 16;   // RNE
    return (unsigned short)r;
}
__device__ __forceinline__ float fast_tanh(float x) {
    return 1.0f - 2.0f / (__expf(2.0f * x) + 1.0f);
}
__device__ __forceinline__ float fast_sigmoid(float x) {
    return 1.0f / (1.0f + __expf(-x));
}
__device__ __forceinline__ float dot4(float4 x, float4 w) {
    return x.x * w.x + x.y * w.y + x.z * w.z + x.w * w.w;
}

// LDS-only barrier: orders LDS producer->consumer across waves WITHOUT
// draining vmcnt. All inter-wave hazards here are LDS (A-tiles, z);
// global loads are consumed same-wave (compiler waits vmcnt before the
// dependent ds_write); global stores are never read back.
__device__ __forceinline__ void lds_barrier() {
    asm volatile("s_waitcnt lgkmcnt(0)" ::: "memory");
    __builtin_amdgcn_s_barrier();
    __builtin_amdgcn_sched_barrier(0);
}

// Convert the three (256x256) fp32 modality weights to bf16 AND pre-arrange in
// MFMA-fragment order so the GEMM's B-loads are lane-linear (fully coalesced):
//   dst chunk (16B = 8 bf16) = ((mod*16 + cg)*8 + ks)*64 + kblk*16 + l15
//   holds src col = cg*16 + l15, k = ks*32 + kblk*8 .. +8
__global__ void wconv_kernel(const float* __restrict__ wa,
                             const float* __restrict__ wv,
                             const float* __restrict__ wl,
                             unsigned short* __restrict__ wb) {
    int i = blockIdx.x * blockDim.x + threadIdx.x;   // src chunk id, 0..24575
    int mod  = i >> 13;                              // 8192 chunks per modality
    int r    = i & 8191;                             // col*32 + ks*4 + kblk
    int col  = r >> 5;
    int ks   = (r >> 2) & 7;
    int kblk = r & 3;
    const float* src = (mod == 0) ? wa : (mod == 1) ? wv : wl;
    const float4* s = (const float4*)(src + col * 256 + ks * 32 + kblk * 8);
    float4 lo = s[0], hi = s[1];
    short8 pk;
    pk[0] = (short)f_to_bfbits(lo.x); pk[1] = (short)f_to_bfbits(lo.y);
    pk[2] = (short)f_to_bfbits(lo.z); pk[3] = (short)f_to_bfbits(lo.w);
    pk[4] = (short)f_to_bfbits(hi.x); pk[5] = (short)f_to_bfbits(hi.y);
    pk[6] = (short)f_to_bfbits(hi.z); pk[7] = (short)f_to_bfbits(hi.w);
    int dst = mod * 8192 + (((col >> 4) * 8 + ks) << 6) + kblk * 16 + (col & 15);
    *(short8*)(wb + dst * 8) = pk;
}

__global__ __launch_bounds__(THREADS, 4)
void fused_kernel(const float* __restrict__ a,
                  const float* __restrict__ v,
                  const float* __restrict__ l,
                  const unsigned short* __restrict__ wbf,   // packed fragments
                  const float* __restrict__ ba,
                  const float* __restrict__ bv,
                  const float* __restrict__ bl,
                  const float* __restrict__ wav, const float* __restrict__ bav,
                  const float* __restrict__ wal, const float* __restrict__ bal,
                  const float* __restrict__ wvl, const float* __restrict__ bvl,
                  float* __restrict__ out) {
    __shared__ __align__(16) unsigned short lds_a[2][3][BM][D_DIM]; // 48 KiB dbuf
    __shared__ float lds_z[2][3][BM];                               // 384 B dbuf
    __shared__ __align__(16) float lds_ob[4][BM * OBROW];           // 17 KiB

    const int tid  = threadIdx.x;
    const int wave = tid >> 6;                  // 0..7
    const int lane = tid & 63;
    const int b    = blockIdx.x >> 3;           // dialogue 0..127
    const int t00  = (blockIdx.x & 7) * (TPB * BM);

    if (wave < 4) {
        // =================== PRODUCER: stage + gates ===================
        const int k0 = lane * 4;
        float4 gav0 = *(const float4*)(wav + k0);
        float4 gav1 = *(const float4*)(wav + 256 + k0);
        float4 gav2 = *(const float4*)(wav + 512 + k0);
        float4 gal0 = *(const float4*)(wal + k0);
        float4 gal1 = *(const float4*)(wal + 256 + k0);
        float4 gal2 = *(const float4*)(wal + 512 + k0);
        float4 gvl0 = *(const float4*)(wvl + k0);
        float4 gvl1 = *(const float4*)(wvl + 256 + k0);
        float4 gvl2 = *(const float4*)(wvl + 512 + k0);
        const float gbav = bav[0], gbal = bal[0], gbvl = bvl[0];

        // stage one tile into buffer buf (R6-proven pattern: batch loads, pack)
        auto stage = [&](int t0, int buf) {
            float4 fa[4], fv[4], fl[4];
#pragma unroll
            for (int i = 0; i < 4; ++i) {
                const int row = wave * 4 + i;
                const size_t gbase = ((size_t)(t0 + row) * B_DLG + b) * D_DIM + lane * 4;
                fa[i] = *(const float4*)(a + gbase);
                fv[i] = *(const float4*)(v + gbase);
                fl[i] = *(const float4*)(l + gbase);
            }
#pragma unroll
            for (int i = 0; i < 4; ++i) {
                const int row = wave * 4 + i;
                const int boff = (lane * 8) ^ ((row & 7) << 4);
                ushort4 pa, pv, pl;
                pa.x = f_to_bfbits(fa[i].x); pa.y = f_to_bfbits(fa[i].y);
                pa.z = f_to_bfbits(fa[i].z); pa.w = f_to_bfbits(fa[i].w);
                pv.x = f_to_bfbits(fv[i].x); pv.y = f_to_bfbits(fv[i].y);
                pv.z = f_to_bfbits(fv[i].z); pv.w = f_to_bfbits(fv[i].w);
                pl.x = f_to_bfbits(fl[i].x); pl.y = f_to_bfbits(fl[i].y);
                pl.z = f_to_bfbits(fl[i].z); pl.w = f_to_bfbits(fl[i].w);
                *(ushort4*)((char*)&lds_a[buf][0][row][0] + boff) = pa;
                *(ushort4*)((char*)&lds_a[buf][1][row][0] + boff) = pv;
                *(ushort4*)((char*)&lds_a[buf][2][row][0] + boff) = pl;

                float4 pav, pal, pvl;
                pav.x = fa[i].x * fv[i].x; pav.y = fa[i].y * fv[i].y;
                pav.z = fa[i].z * fv[i].z; pav.w = fa[i].w * fv[i].w;
                pal.x = fa[i].x * fl[i].x; pal.y = fa[i].y * fl[i].y;
                pal.z = fa[i].z * fl[i].z; pal.w = fa[i].w * fl[i].w;
                pvl.x = fv[i].x * fl[i].x; pvl.y = fv[i].y * fl[i].y;
                pvl.z = fv[i].z * fl[i].z; pvl.w = fv[i].w * fl[i].w;
                float s_av = dot4(fa[i], gav0) + dot4(fv[i], gav1) + dot4(pav, gav2);
                float s_al = dot4(fa[i], gal0) + dot4(fl[i], gal1) + dot4(pal, gal2);
                float s_vl = dot4(fv[i], gvl0) + dot4(fl[i], gvl1) + dot4(pvl, gvl2);
#pragma unroll
                for (int off = 1; off < 64; off <<= 1) {
                    s_av += __shfl_xor(s_av, off);
                    s_al += __shfl_xor(s_al, off);
                    s_vl += __shfl_xor(s_vl, off);
                }
                if (lane == 0) {
                    lds_z[buf][0][row] = fast_sigmoid(s_av + gbav);
                    lds_z[buf][1][row] = fast_sigmoid(s_al + gbal);
                    lds_z[buf][2][row] = fast_sigmoid(s_vl + gbvl);
                }
            }
        };

        stage(t00, 0);
        lds_barrier();                               // B0: buf0 ready
#pragma unroll 1
        for (int t = 0; t < TPB; ++t) {
            if (t + 1 < TPB) stage(t00 + (t + 1) * BM, (t + 1) & 1);
            lds_barrier();                           // Bt: next buf ready
        }
    } else {
        // =================== CONSUMER: GEMM + epilogue ===================
        const int cw   = wave - 4;                   // 0..3
        const int l15  = lane & 15;
        const int kblk = lane >> 4;
        float bba[4], bbv[4], bbl[4];
#pragma unroll
        for (int ct = 0; ct < 4; ++ct) {
            const int col = cw * 64 + ct * 16 + l15;
            bba[ct] = ba[col]; bbv[ct] = bv[col]; bbl[ct] = bl[col];
        }
        float* ob = lds_ob[cw];

        lds_barrier();                               // B0
#pragma unroll 1
        for (int t = 0; t < TPB; ++t) {
            const int t0  = t00 + t * BM;
            const int buf = t & 1;

            f32x4 acc[3][4];
#pragma unroll
            for (int m = 0; m < 3; ++m)
#pragma unroll
                for (int ct = 0; ct < 4; ++ct)
                    acc[m][ct] = (f32x4){0.f, 0.f, 0.f, 0.f};

#pragma unroll 2
            for (int ks = 0; ks < KSTEPS; ++ks) {
                int kbyte = ks * 64 + kblk * 16;
#pragma unroll
                for (int mod = 0; mod < 3; ++mod) {
                    int bo = kbyte ^ ((l15 & 7) << 4);
                    short8 afrag = *(const short8*)
                        ((const char*)&lds_a[buf][mod][l15][0] + bo);
#pragma unroll
                    for (int ct = 0; ct < 4; ++ct) {
                        const unsigned short* bp = wbf +
                            ((size_t)(((mod * 16 + cw * 4 + ct) * 8 + ks) * 64) + lane) * 8;
                        short8 bfrag = *(const short8*)bp;
                        acc[mod][ct] = __builtin_amdgcn_mfma_f32_16x16x32_bf16(
                            afrag, bfrag, acc[mod][ct], 0, 0, 0);
                    }
                }
            }

            // tanh once, in place
#pragma unroll
            for (int ct = 0; ct < 4; ++ct)
#pragma unroll
                for (int r = 0; r < 4; ++r) {
                    acc[0][ct][r] = fast_tanh(acc[0][ct][r] + bba[ct]);
                    acc[1][ct][r] = fast_tanh(acc[1][ct][r] + bbv[ct]);
                    acc[2][ct][r] = fast_tanh(acc[2][ct][r] + bbl[ct]);
                }

            const size_t rowbase = (size_t)b * L_SEQ + t0;
#pragma unroll
            for (int sec = 0; sec < 3; ++sec) {
                const int mA = (sec == 2) ? 1 : 0;
                const int mB = (sec == 0) ? 1 : 2;
#pragma unroll
                for (int ct = 0; ct < 4; ++ct)
#pragma unroll
                    for (int r = 0; r < 4; ++r) {
                        const int row = kblk * 4 + r;
                        const float h1 = acc[mA][ct][r];
                        const float h2 = acc[mB][ct][r];
                        const float z  = lds_z[buf][sec][row];
                        ob[row * OBROW + ct * 16 + l15] = h2 + z * (h1 - h2);
                    }
                // same-wave cross-lane LDS RAW: complete + order
                asm volatile("s_waitcnt lgkmcnt(0)" ::: "memory");
                __builtin_amdgcn_sched_barrier(0);
                // full-line stores: 8-lane group covers one 128B line
#pragma unroll
                for (int q = 0; q < 2; ++q) {
#pragma unroll
                    for (int ch = 0; ch < 2; ++ch) {
                        const int rt   = q * 8 + (lane >> 3);
                        const int colq = lane & 7;
                        float4 val = *(const float4*)&ob[rt * OBROW + ch * 32 + colq * 4];
                        *(float4*)(out + (rowbase + rt) * (3 * D_DIM)
                                       + sec * D_DIM + cw * 64 + ch * 32 + colq * 4) = val;
                    }
                }
            }
            lds_barrier();                           // Bt
        }
    }
}

extern "C" void kernel_launch(void* const* d_in, const int* in_sizes, int n_in,
                              void* d_out, int out_size, void* d_ws, size_t ws_size,
                              hipStream_t stream) {
    const float* a   = (const float*)d_in[0];
    const float* v   = (const float*)d_in[1];
    const float* l   = (const float*)d_in[2];
    // d_in[3] = lengths (all == L, static shape -> unused)
    const float* Wa  = (const float*)d_in[4];
    const float* ba  = (const float*)d_in[5];
    const float* Wv  = (const float*)d_in[6];
    const float* bv  = (const float*)d_in[7];
    const float* Wl  = (const float*)d_in[8];
    const float* bl  = (const float*)d_in[9];
    const float* Wav = (const float*)d_in[10];
    const float* bav = (const float*)d_in[11];
    const float* Wal = (const float*)d_in[12];
    const float* bal = (const float*)d_in[13];
    const float* Wvl = (const float*)d_in[14];
    const float* bvl = (const float*)d_in[15];
    float* out = (float*)d_out;

    unsigned short* wb = (unsigned short*)d_ws;   // needs 3*65536*2 = 384 KiB

    hipLaunchKernelGGL(wconv_kernel, dim3(96), dim3(256), 0, stream, Wa, Wv, Wl, wb);
    hipLaunchKernelGGL(fused_kernel, dim3(NBLK), dim3(THREADS), 0, stream,
                       a, v, l, wb, ba, bv, bl, Wav, bav, Wal, bal, Wvl, bvl, out);
}

// Round 12
// 255.367 us; speedup vs baseline: 1.8743x; 1.8743x over previous
//
#include <hip/hip_runtime.h>
#include <hip/hip_bf16.h>

// Problem constants (fixed by reference)
#define L_SEQ 1024
#define B_DLG 128
#define D_DIM 256
#define BM 32            // rows per block tile
#define THREADS 512      // 8 waves
#define KSTEPS 8         // 256 / 32
#define NTILES (L_SEQ / BM)             // 32 row-tiles per dialogue
#define NBLK (B_DLG * NTILES)           // 4096 blocks
#define OBROW 36         // dwords per OB row slice (32 cols + pad), 16B aligned

typedef __attribute__((ext_vector_type(8))) short short8;   // 8 bf16 (4 VGPRs)
typedef __attribute__((ext_vector_type(4))) float f32x4;    // MFMA accumulator

__device__ __forceinline__ unsigned short f_to_bfbits(float f) {
    unsigned int u = __float_as_uint(f);
    unsigned int r = (u + 0x7FFFu + ((u >> 16) & 1u)) >> 16;   // RNE
    return (unsigned short)r;
}
__device__ __forceinline__ float fast_tanh(float x) {
    return 1.0f - 2.0f / (__expf(2.0f * x) + 1.0f);
}
__device__ __forceinline__ float fast_sigmoid(float x) {
    return 1.0f / (1.0f + __expf(-x));
}
__device__ __forceinline__ float dot4(float4 x, float4 w) {
    return x.x * w.x + x.y * w.y + x.z * w.z + x.w * w.w;
}

// LDS-only barrier: orders LDS producer->consumer across waves WITHOUT
// draining vmcnt (global stores keep draining in background; global loads
// are same-wave consumed so the compiler's own vmcnt waits cover them).
__device__ __forceinline__ void lds_barrier() {
    asm volatile("s_waitcnt lgkmcnt(0)" ::: "memory");
    __builtin_amdgcn_s_barrier();
    __builtin_amdgcn_sched_barrier(0);
}

// Convert the three (256x256) fp32 modality weights to bf16 AND pre-arrange in
// MFMA-fragment order so the GEMM's B-loads are lane-linear (fully coalesced):
//   dst chunk (16B = 8 bf16) = ((mod*16 + cg)*8 + ks)*64 + kblk*16 + l15
//   holds src col = cg*16 + l15, k = ks*32 + kblk*8 .. +8
__global__ void wconv_kernel(const float* __restrict__ wa,
                             const float* __restrict__ wv,
                             const float* __restrict__ wl,
                             unsigned short* __restrict__ wb) {
    int i = blockIdx.x * blockDim.x + threadIdx.x;   // src chunk id, 0..24575
    int mod  = i >> 13;                              // 8192 chunks per modality
    int r    = i & 8191;                             // col*32 + ks*4 + kblk
    int col  = r >> 5;
    int ks   = (r >> 2) & 7;
    int kblk = r & 3;
    const float* src = (mod == 0) ? wa : (mod == 1) ? wv : wl;
    const float4* s = (const float4*)(src + col * 256 + ks * 32 + kblk * 8);
    float4 lo = s[0], hi = s[1];
    short8 pk;
    pk[0] = (short)f_to_bfbits(lo.x); pk[1] = (short)f_to_bfbits(lo.y);
    pk[2] = (short)f_to_bfbits(lo.z); pk[3] = (short)f_to_bfbits(lo.w);
    pk[4] = (short)f_to_bfbits(hi.x); pk[5] = (short)f_to_bfbits(hi.y);
    pk[6] = (short)f_to_bfbits(hi.z); pk[7] = (short)f_to_bfbits(hi.w);
    int dst = mod * 8192 + (((col >> 4) * 8 + ks) << 6) + kblk * 16 + (col & 15);
    *(short8*)(wb + dst * 8) = pk;
}

__global__ __launch_bounds__(THREADS, 4)
void fused_kernel(const float* __restrict__ a,
                  const float* __restrict__ v,
                  const float* __restrict__ l,
                  const unsigned short* __restrict__ wbf,   // packed fragments
                  const float* __restrict__ ba,
                  const float* __restrict__ bv,
                  const float* __restrict__ bl,
                  const float* __restrict__ wav, const float* __restrict__ bav,
                  const float* __restrict__ wal, const float* __restrict__ bal,
                  const float* __restrict__ wvl, const float* __restrict__ bvl,
                  float* __restrict__ out) {
    // A-tiles bf16 (3*32*256*2 = 49152 B), aliased post-GEMM by per-wave OB
    // slices (8 waves * 32*36*4 = 36864 B). One lds_barrier separates uses.
    __shared__ __align__(16) char lds_raw[3 * BM * D_DIM * 2];
    __shared__ float lds_z[3][BM];
#define LDS_A ((unsigned short (*)[BM][D_DIM])lds_raw)

    const int tid  = threadIdx.x;
    const int wave = tid >> 6;
    const int lane = tid & 63;
    const int b    = blockIdx.x >> 5;                  // dialogue 0..127
    const int t0   = (blockIdx.x & (NTILES - 1)) * BM; // row-tile start

    // ---------------- stage: issue ALL global loads first (MLP) ----------------
    float4 fa[4], fv[4], fl[4];
#pragma unroll
    for (int i = 0; i < BM / 8; ++i) {
        const int row = wave + 8 * i;
        const size_t gbase = ((size_t)(t0 + row) * B_DLG + b) * D_DIM + lane * 4;
        fa[i] = *(const float4*)(a + gbase);
        fv[i] = *(const float4*)(v + gbase);
        fl[i] = *(const float4*)(l + gbase);
    }

    // gate weights for this lane's 4 k-values
    const int k0 = lane * 4;
    float4 gav0 = *(const float4*)(wav + k0);
    float4 gav1 = *(const float4*)(wav + 256 + k0);
    float4 gav2 = *(const float4*)(wav + 512 + k0);
    float4 gal0 = *(const float4*)(wal + k0);
    float4 gal1 = *(const float4*)(wal + 256 + k0);
    float4 gal2 = *(const float4*)(wal + 512 + k0);
    float4 gvl0 = *(const float4*)(wvl + k0);
    float4 gvl1 = *(const float4*)(wvl + 256 + k0);
    float4 gvl2 = *(const float4*)(wvl + 512 + k0);

    // ---------------- pack -> LDS (swizzled) + fused gates ----------------
    {
        const int swz = (wave & 7) << 4;
        const int boff = (lane * 8) ^ swz;
#pragma unroll
        for (int i = 0; i < BM / 8; ++i) {
            const int row = wave + 8 * i;
            ushort4 pa, pv, pl;
            pa.x = f_to_bfbits(fa[i].x); pa.y = f_to_bfbits(fa[i].y);
            pa.z = f_to_bfbits(fa[i].z); pa.w = f_to_bfbits(fa[i].w);
            pv.x = f_to_bfbits(fv[i].x); pv.y = f_to_bfbits(fv[i].y);
            pv.z = f_to_bfbits(fv[i].z); pv.w = f_to_bfbits(fv[i].w);
            pl.x = f_to_bfbits(fl[i].x); pl.y = f_to_bfbits(fl[i].y);
            pl.z = f_to_bfbits(fl[i].z); pl.w = f_to_bfbits(fl[i].w);
            *(ushort4*)((char*)&LDS_A[0][row][0] + boff) = pa;
            *(ushort4*)((char*)&LDS_A[1][row][0] + boff) = pv;
            *(ushort4*)((char*)&LDS_A[2][row][0] + boff) = pl;

            float4 pav, pal, pvl;
            pav.x = fa[i].x * fv[i].x; pav.y = fa[i].y * fv[i].y;
            pav.z = fa[i].z * fv[i].z; pav.w = fa[i].w * fv[i].w;
            pal.x = fa[i].x * fl[i].x; pal.y = fa[i].y * fl[i].y;
            pal.z = fa[i].z * fl[i].z; pal.w = fa[i].w * fl[i].w;
            pvl.x = fv[i].x * fl[i].x; pvl.y = fv[i].y * fl[i].y;
            pvl.z = fv[i].z * fl[i].z; pvl.w = fv[i].w * fl[i].w;
            float s_av = dot4(fa[i], gav0) + dot4(fv[i], gav1) + dot4(pav, gav2);
            float s_al = dot4(fa[i], gal0) + dot4(fl[i], gal1) + dot4(pal, gal2);
            float s_vl = dot4(fv[i], gvl0) + dot4(fl[i], gvl1) + dot4(pvl, gvl2);

#pragma unroll
            for (int off = 1; off < 64; off <<= 1) {
                s_av += __shfl_xor(s_av, off);
                s_al += __shfl_xor(s_al, off);
                s_vl += __shfl_xor(s_vl, off);
            }
            if (lane == 0) {
                lds_z[0][row] = fast_sigmoid(s_av + bav[0]);
                lds_z[1][row] = fast_sigmoid(s_al + bal[0]);
                lds_z[2][row] = fast_sigmoid(s_vl + bvl[0]);
            }
        }
    }
    lds_barrier();   // A-tiles + z ready (LDS-only hazard)

    // ---------------- GEMM K-loop: 3 modalities, wave owns 32 cols ----------------
    f32x4 acc[3][2][2];
#pragma unroll
    for (int m = 0; m < 3; ++m)
#pragma unroll
        for (int mt = 0; mt < 2; ++mt)
#pragma unroll
            for (int ct = 0; ct < 2; ++ct)
                acc[m][mt][ct] = (f32x4){0.f, 0.f, 0.f, 0.f};

    const int l15 = lane & 15;
    const int kblk = lane >> 4;          // 0..3
    const int colbase = wave * 32;

#pragma unroll 2
    for (int ks = 0; ks < KSTEPS; ++ks) {
        int kbyte = ks * 64 + kblk * 16;
#pragma unroll
        for (int mod = 0; mod < 3; ++mod) {
            short8 afrag[2];
#pragma unroll
            for (int mt = 0; mt < 2; ++mt) {
                int row = mt * 16 + l15;
                int bo = kbyte ^ ((row & 7) << 4);
                afrag[mt] = *(const short8*)((const char*)&LDS_A[mod][row][0] + bo);
            }
#pragma unroll
            for (int ct = 0; ct < 2; ++ct) {
                const unsigned short* bp = wbf +
                    ((size_t)(((mod * 16 + wave * 2 + ct) * 8 + ks) * 64) + lane) * 8;
                short8 bfrag = *(const short8*)bp;
#pragma unroll
                for (int mt = 0; mt < 2; ++mt)
                    acc[mod][mt][ct] = __builtin_amdgcn_mfma_f32_16x16x32_bf16(
                        afrag[mt], bfrag, acc[mod][mt][ct], 0, 0, 0);
            }
        }
    }

    lds_barrier();   // all A-tile reads done -> OB may alias lds_raw

    // ---------------- epilogue: tanh once, per-wave OB, full-line stores ------
    const int col0 = colbase + l15, col1 = colbase + 16 + l15;
    const float bba0 = ba[col0], bba1 = ba[col1];
    const float bbv0 = bv[col0], bbv1 = bv[col1];
    const float bbl0 = bl[col0], bbl1 = bl[col1];

#pragma unroll
    for (int mt = 0; mt < 2; ++mt)
#pragma unroll
        for (int ct = 0; ct < 2; ++ct)
#pragma unroll
            for (int r = 0; r < 4; ++r) {
                acc[0][mt][ct][r] = fast_tanh(acc[0][mt][ct][r] + (ct ? bba1 : bba0));
                acc[1][mt][ct][r] = fast_tanh(acc[1][mt][ct][r] + (ct ? bbv1 : bbv0));
                acc[2][mt][ct][r] = fast_tanh(acc[2][mt][ct][r] + (ct ? bbl1 : bbl0));
            }

    float* ob = (float*)lds_raw + wave * (BM * OBROW);   // 4608 B per wave
    const size_t rowbase = (size_t)b * L_SEQ + t0;

#pragma unroll
    for (int sec = 0; sec < 3; ++sec) {
        const int mA = (sec == 2) ? 1 : 0;       // h1 source modality
        const int mB = (sec == 0) ? 1 : 2;       // h2 source modality
#pragma unroll
        for (int mt = 0; mt < 2; ++mt)
#pragma unroll
            for (int ct = 0; ct < 2; ++ct)
#pragma unroll
                for (int r = 0; r < 4; ++r) {
                    const int row = mt * 16 + kblk * 4 + r;
                    const float h1 = acc[mA][mt][ct][r];
                    const float h2 = acc[mB][mt][ct][r];
                    const float z  = lds_z[sec][row];
                    ob[row * OBROW + ct * 16 + l15] = h2 + z * (h1 - h2);
                }
        // same-wave cross-lane LDS RAW: complete + keep order
        asm volatile("s_waitcnt lgkmcnt(0)" ::: "memory");
        __builtin_amdgcn_sched_barrier(0);
        // full-line stores: each 8-lane group covers one 128B line
        // base = row*3072 + sec*1024 + wave*128 (all 128B-aligned)
#pragma unroll
        for (int q = 0; q < 4; ++q) {
            const int rt   = q * 8 + (lane >> 3);      // row 0..31
            const int colq = lane & 7;                 // float4 slot within 32 cols
            float4 val = *(const float4*)&ob[rt * OBROW + colq * 4];
            *(float4*)(out + (rowbase + rt) * (3 * D_DIM)
                           + sec * D_DIM + wave * 32 + colq * 4) = val;
        }
    }
#undef LDS_A
}

extern "C" void kernel_launch(void* const* d_in, const int* in_sizes, int n_in,
                              void* d_out, int out_size, void* d_ws, size_t ws_size,
                              hipStream_t stream) {
    const float* a   = (const float*)d_in[0];
    const float* v   = (const float*)d_in[1];
    const float* l   = (const float*)d_in[2];
    // d_in[3] = lengths (all == L, static shape -> unused)
    const float* Wa  = (const float*)d_in[4];
    const float* ba  = (const float*)d_in[5];
    const float* Wv  = (const float*)d_in[6];
    const float* bv  = (const float*)d_in[7];
    const float* Wl  = (const float*)d_in[8];
    const float* bl  = (const float*)d_in[9];
    const float* Wav = (const float*)d_in[10];
    const float* bav = (const float*)d_in[11];
    const float* Wal = (const float*)d_in[12];
    const float* bal = (const float*)d_in[13];
    const float* Wvl = (const float*)d_in[14];
    const float* bvl = (const float*)d_in[15];
    float* out = (float*)d_out;

    unsigned short* wb = (unsigned short*)d_ws;   // needs 3*65536*2 = 384 KiB

    hipLaunchKernelGGL(wconv_kernel, dim3(96), dim3(256), 0, stream, Wa, Wv, Wl, wb);
    hipLaunchKernelGGL(fused_kernel, dim3(NBLK), dim3(THREADS), 0, stream,
                       a, v, l, wb, ba, bv, bl, Wav, bav, Wal, bal, Wvl, bvl, out);
}